// Round 3
// baseline (267.798 us; speedup 1.0000x reference)
//
#include <hip/hip_runtime.h>

// Fused 2-layer GRU, round 15: resubmit of R14 (infra failure, no data).
// R13 + wave-pair r-split for 4 waves/SIMD. S=256, B=8192, IN=1, H=32, L=2.
//
// 512 blocks x 512 thr (8 waves); block owns 16 batch elements.
// Waves form pairs: w = 2*role + sub. role 0,1 -> layer 0 halves (wl);
// role 2,3 -> layer 1 halves. Pair members issue IDENTICAL MFMAs (MFMA
// issue is cheap, 13% util) but each combines only 2 of the 4 accumulator
// elements (sub=0 -> r{0,1}, sub=1 -> r{2,3}) and writes one packed u32.
// This halves per-wave VALU/trans work and doubles occupancy (2->4
// waves/SIMD) to fill the ~34% barrier/latency bubble observed in R13.
//
// Layer 0 = true-dependency path, s_setprio(1). Layer 1 lagged one step,
// ih-side MFMAs chained onto hh-side accumulators. y-head MFMA rotates
// over waves 4..7 by timestep parity. Merged-rcp gate math (5 trans/elem):
//   h' = [Nx*Nz - 2*Ez + (h-1)*Nx] * rcp(Nx*Nz)
// hm = h-1 kept in registers (2 elems/lane).

#define S_LEN 256
#define B_SZ  8192
#define H_SZ  32
#define RS    40     // LDS row stride in shorts (80 B)

typedef __attribute__((ext_vector_type(8))) short short8;  // 8 bf16
typedef __attribute__((ext_vector_type(4))) float f32x4;   // MFMA C/D

#define MFMA(a, b, c) __builtin_amdgcn_mfma_f32_16x16x32_bf16(a, b, c, 0, 0, 0)

__device__ __forceinline__ unsigned short bf_rne1(float f) {
    union { float f; unsigned u; } x; x.f = f;
    unsigned u = x.u + 0x7fffu + ((x.u >> 16) & 1u);
    return (unsigned short)(u >> 16);
}

#if __has_builtin(__builtin_amdgcn_cvt_pk_bf16_f32)
typedef __bf16 bf16x2 __attribute__((ext_vector_type(2)));
__device__ __forceinline__ unsigned pk2(float a, float b) {
    union { bf16x2 v; unsigned u; } c;
    c.v = __builtin_amdgcn_cvt_pk_bf16_f32(a, b);
    return c.u;
}
#else
__device__ __forceinline__ unsigned pk2(float a, float b) {
    return (unsigned)bf_rne1(a) | ((unsigned)bf_rne1(b) << 16);
}
#endif

union Frag8 { short8 s8; unsigned u[4]; };

// Merged-rcp GRU combine on TWO elements (one r-pair). 5 trans/elem.
// dr,dz carry -log2e*(preact); dn,dxn carry 2log2e*(hh / ih parts of n).
// hm[j] = h-1 (updated in place). Returns packed bf16 pair.
__device__ __forceinline__ unsigned gru_comb2(const float dr[2], const float dz[2],
                                              const float dn[2], const float dxn[2],
                                              float* hm) {
    float v[2];
#pragma unroll
    for (int j = 0; j < 2; ++j) {
        const float Er = __builtin_amdgcn_exp2f(dr[j]);
        const float rg = __builtin_amdgcn_rcpf(1.0f + Er);           // r gate
        const float X  = __builtin_amdgcn_exp2f(fmaf(rg, dn[j], dxn[j]));
        const float Ez = __builtin_amdgcn_exp2f(dz[j]);
        const float Nx = 1.0f + X;            // tanh denom
        const float Nz = 1.0f + Ez;           // z denom
        const float P  = Nx * Nz;
        float num = fmaf(-2.0f, Ez, P);       // Nx*Nz - 2*Ez
        num = fmaf(hm[j], Nx, num);           // + (h-1)*Nx
        const float vv = num * __builtin_amdgcn_rcpf(P);
        hm[j] = vv - 1.0f;
        v[j] = vv;
    }
    return pk2(v[0], v[1]);
}

// Select the r-pair under a wave-uniform branch (static vector indices only).
__device__ __forceinline__ unsigned comb_sel(int sub, const f32x4& Dr, const f32x4& Dz,
                                             const f32x4& Dn, const f32x4& Dxn,
                                             float* hm) {
    if (sub == 0) {
        const float dr[2]  = {Dr[0], Dr[1]},  dz[2]  = {Dz[0], Dz[1]};
        const float dn[2]  = {Dn[0], Dn[1]},  dxn[2] = {Dxn[0], Dxn[1]};
        return gru_comb2(dr, dz, dn, dxn, hm);
    } else {
        const float dr[2]  = {Dr[2], Dr[3]},  dz[2]  = {Dz[2], Dz[3]};
        const float dn[2]  = {Dn[2], Dn[3]},  dxn[2] = {Dxn[2], Dxn[3]};
        return gru_comb2(dr, dz, dn, dxn, hm);
    }
}

__global__ __launch_bounds__(512) void gru_xm(
    const float* __restrict__ x,      // (S,B,1)
    const float* __restrict__ h_in,   // (2,B,H)
    const float* __restrict__ W_ih0,  // (96,1)
    const float* __restrict__ W_hh0,  // (96,32)
    const float* __restrict__ b_ih0,  // (96)
    const float* __restrict__ b_hh0,  // (96)
    const float* __restrict__ W_ih1,  // (96,32)
    const float* __restrict__ W_hh1,  // (96,32)
    const float* __restrict__ b_ih1,  // (96)
    const float* __restrict__ b_hh1,  // (96)
    const float* __restrict__ W_out,  // (1,32)
    const float* __restrict__ b_out,  // (1)
    float* __restrict__ out)          // y (S*B) then h_state (2,B,H)
{
    __shared__ __align__(16) unsigned short sh0[2][16 * RS];  // h0 bf16
    __shared__ __align__(16) unsigned short sh1[2][16 * RS];  // h1 bf16
    __shared__ __align__(16) float sx[(S_LEN + 1) * 16];      // staged x (+pad)
    __shared__ __align__(16) float sy[S_LEN * 16];            // buffered y

    const int tid  = threadIdx.x;
    const int w    = tid >> 6;        // 0..7
    const int sub  = w & 1;           // r-pair selector within wave-pair
    const int lane = tid & 63;
    const int n    = lane & 15;       // batch col / A-row index
    const int q    = lane >> 4;       // quad
    const int base = blockIdx.x * 16;
    const int bn   = base + n;
    const int wl   = (w >> 1) & 1;    // hidden half within the layer
    const bool L0  = (w < 4);

    // ---- stage x (coalesced float4, all waves) ----
    for (int s = tid; s < S_LEN * 4; s += 512) {
        const int t = s >> 2, c = s & 3;
        *(float4*)&sx[t * 16 + c * 4] = *(const float4*)&x[t * B_SZ + base + c * 4];
    }

    const float SRZ = -1.4426950408889634f;  // -log2(e)   (sigmoid gates)
    const float SN  =  2.8853900817779268f;  //  2*log2(e) (tanh gate)

    // ---- per-role persistent weights ----
    short8 A_h[3], A_i[3];                        // recurrent / (L1 ih | L0 x)
    f32x4  C_h[3], C_i3;
    short8 Awo = {0, 0, 0, 0, 0, 0, 0, 0};        // y head A-frag (waves 4..7)
    short8 Bx  = {0, 0, 0, 0, 0, 0, 0, 0};        // x B-frag (L0), k=0 slot
    float  hm[2];                                  // own 2 h elems - 1, fp32

    if (L0) {
#pragma unroll
        for (int t = 0; t < 3; ++t) {
            const float sc = (t < 2) ? SRZ : SN;
            const int row = 32 * t + 16 * wl + n;
#pragma unroll
            for (int e = 0; e < 8; ++e)
                A_h[t][e] = (short)bf_rne1(W_hh0[row * H_SZ + q * 8 + e] * sc);
            // one-column x-weight fragment: k=0 only (q==0 && e==0)
#pragma unroll
            for (int e = 0; e < 8; ++e)
                A_i[t][e] = (q == 0 && e == 0)
                            ? (short)bf_rne1(W_ih0[row] * sc) : (short)0;
#pragma unroll
            for (int r = 0; r < 4; ++r) {
                const int g = 32 * t + 16 * wl + 4 * q + r;
                C_h[t][r] = (t < 2) ? SRZ * (b_ih0[g] + b_hh0[g])
                                    : SN * b_hh0[g];
                if (t == 2) C_i3[r] = SN * b_ih0[g];   // n-gate ih bias
            }
        }
#pragma unroll
        for (int j = 0; j < 2; ++j)
            hm[j] = h_in[bn * H_SZ + 16 * wl + 4 * q + 2 * sub + j] - 1.0f;
    } else {
#pragma unroll
        for (int t = 0; t < 3; ++t) {
            const float sc = (t < 2) ? SRZ : SN;
            const int row = 32 * t + 16 * wl + n;
#pragma unroll
            for (int e = 0; e < 8; ++e) {
                A_h[t][e] = (short)bf_rne1(W_hh1[row * H_SZ + q * 8 + e] * sc);
                A_i[t][e] = (short)bf_rne1(W_ih1[row * H_SZ + q * 8 + e] * sc);
            }
#pragma unroll
            for (int r = 0; r < 4; ++r) {
                const int g = 32 * t + 16 * wl + 4 * q + r;
                C_h[t][r] = (t < 2) ? SRZ * (b_ih1[g] + b_hh1[g])
                                    : SN * b_hh1[g];
                if (t == 2) C_i3[r] = SN * b_ih1[g];
            }
        }
#pragma unroll
        for (int j = 0; j < 2; ++j)
            hm[j] = h_in[B_SZ * H_SZ + bn * H_SZ + 16 * wl + 4 * q + 2 * sub + j] - 1.0f;
        // y-head fragment on all L1 waves (rotating timesteps)
#pragma unroll
        for (int e = 0; e < 8; ++e)
            Awo[e] = (n == 0) ? (short)bf_rne1(W_out[q * 8 + e]) : (short)0;
    }
    const f32x4 Z4 = {0.f, 0.f, 0.f, 0.f};
    const float bout = b_out[0];

    // ---- initial B fragments (bf16 from h_in) ----
    short8 B0, B1;   // L0: B0 = h0(i-1). L1: B0 = h0(i-1), B1 = h1(i-2).
    {
        const float* hsrc = h_in + (size_t)(!L0) * B_SZ * H_SZ + bn * H_SZ + q * 8;
        Frag8 f;
        const float4 a = *(const float4*)&hsrc[0];
        const float4 b = *(const float4*)&hsrc[4];
        f.u[0] = pk2(a.x, a.y); f.u[1] = pk2(a.z, a.w);
        f.u[2] = pk2(b.x, b.y); f.u[3] = pk2(b.z, b.w);
        if (L0) B0 = f.s8; else B1 = f.s8;
    }

    const int wroff = n * RS + 16 * wl + 4 * q + 2 * sub;  // b32 write (shorts)
    const int rdoff = n * RS + 8 * q;                      // b128 read (shorts)

    __syncthreads();   // x staged
    float xcur = sx[n];
    if (L0) __builtin_amdgcn_s_setprio(1);   // true-dep path issues first

    // ================= iter 0 (peeled): L0 computes h0(0) =================
    if (L0) {
        Frag8 bxu; bxu.s8 = Bx; bxu.u[0] = pk2(xcur, xcur); Bx = bxu.s8;
        f32x4 Dr = MFMA(A_h[0], B0, C_h[0]);  Dr = MFMA(A_i[0], Bx, Dr);
        f32x4 Dz = MFMA(A_h[1], B0, C_h[1]);  Dz = MFMA(A_i[1], Bx, Dz);
        f32x4 Dn = MFMA(A_h[2], B0, C_h[2]);
        f32x4 Dxn = MFMA(A_i[2], Bx, C_i3);
        *(unsigned*)&sh0[0][wroff] = comb_sel(sub, Dr, Dz, Dn, Dxn, hm);
        xcur = sx[16 + n];   // x(1)
    }
    __syncthreads();
    B0 = *(const short8*)&sh0[0][rdoff];   // h0(0) for all waves

    // ================= hot loop i = 1 .. S-1 (no predication) ==============
#pragma unroll 2
    for (int i = 1; i < S_LEN; ++i) {
        const int buf = i & 1;
        if (L0) {
            // h0(i) from B0 = h0(i-1): the true-dependency path.
            Frag8 bxu; bxu.s8 = Bx; bxu.u[0] = pk2(xcur, xcur); Bx = bxu.s8;
            f32x4 Dr = MFMA(A_h[0], B0, C_h[0]);  Dr = MFMA(A_i[0], Bx, Dr);
            f32x4 Dz = MFMA(A_h[1], B0, C_h[1]);  Dz = MFMA(A_i[1], Bx, Dz);
            f32x4 Dn = MFMA(A_h[2], B0, C_h[2]);
            f32x4 Dxn = MFMA(A_i[2], Bx, C_i3);
            *(unsigned*)&sh0[buf][wroff] = comb_sel(sub, Dr, Dz, Dn, Dxn, hm);
            xcur = sx[(i + 1) * 16 + n];   // read-only prefetch, pre-barrier
        } else {
            // h1(i-1) from B1 = h1(i-2), B0 = h0(i-1): prefetched last iter.
            // ih-side chained onto hh-side accumulators (no combine-adds).
            f32x4 Gr = MFMA(A_h[0], B1, C_h[0]);  Gr = MFMA(A_i[0], B0, Gr);
            f32x4 Gz = MFMA(A_h[1], B1, C_h[1]);  Gz = MFMA(A_i[1], B0, Gz);
            f32x4 Un = MFMA(A_h[2], B1, C_h[2]);
            f32x4 Vn = MFMA(A_i[2], B0, C_i3);
            *(unsigned*)&sh1[buf][wroff] = comb_sel(sub, Gr, Gz, Un, Vn, hm);
        }

        __syncthreads();   // lgkm-only drain

        if (L0) {
            B0 = *(const short8*)&sh0[buf][rdoff];          // h0(i)
        } else {
            B0 = *(const short8*)&sh0[buf][rdoff];          // h0(i)
            B1 = *(const short8*)&sh1[buf][rdoff];          // h1(i-1)
            if (w == 4 + ((i - 1) & 3)) {
                // y(i-1) = W_out . h1(i-1): one MFMA, row 0 = result.
                // Rotates over waves 4..7 so no wave straggles every iter.
                const f32x4 yD = MFMA(Awo, B1, Z4);
                if (lane < 16) sy[(i - 1) * 16 + n] = yD[0];
            }
        }
    }

    // ================= iter S (peeled): L1 computes h1(S-1) ================
    if (!L0) {
        f32x4 Gr = MFMA(A_h[0], B1, C_h[0]);  Gr = MFMA(A_i[0], B0, Gr);
        f32x4 Gz = MFMA(A_h[1], B1, C_h[1]);  Gz = MFMA(A_i[1], B0, Gz);
        f32x4 Un = MFMA(A_h[2], B1, C_h[2]);
        f32x4 Vn = MFMA(A_i[2], B0, C_i3);
        *(unsigned*)&sh1[0][wroff] = comb_sel(sub, Gr, Gz, Un, Vn, hm);
    }
    __syncthreads();
    if (w == 4 + ((S_LEN - 1) & 3)) {
        B1 = *(const short8*)&sh1[0][rdoff];               // h1(S-1)
        const f32x4 yD = MFMA(Awo, B1, Z4);
        if (lane < 16) sy[(S_LEN - 1) * 16 + n] = yD[0];
    }
    __syncthreads();   // sy complete

    // ---- flush y (coalesced float4 + bias) ----
    for (int s = tid; s < S_LEN * 4; s += 512) {
        const int t = s >> 2, c = s & 3;
        const float4 a = *(const float4*)&sy[t * 16 + c * 4];
        *(float4*)&out[t * B_SZ + base + c * 4] =
            make_float4(a.x + bout, a.y + bout, a.z + bout, a.w + bout);
    }

    // ---- final h_state: out = y (S*B) ++ h0 (B*H) ++ h1 (B*H) ----
    const size_t hoff = (size_t)S_LEN * B_SZ + (size_t)(!L0) * B_SZ * H_SZ;
    *(float2*)&out[hoff + bn * H_SZ + 16 * wl + 4 * q + 2 * sub] =
        make_float2(hm[0] + 1.0f, hm[1] + 1.0f);
}

extern "C" void kernel_launch(void* const* d_in, const int* in_sizes, int n_in,
                              void* d_out, int out_size, void* d_ws, size_t ws_size,
                              hipStream_t stream) {
    (void)in_sizes; (void)n_in; (void)out_size; (void)d_ws; (void)ws_size;
    const float* x     = (const float*)d_in[0];
    const float* h_in  = (const float*)d_in[1];
    const float* W_ih0 = (const float*)d_in[2];
    const float* W_hh0 = (const float*)d_in[3];
    const float* b_ih0 = (const float*)d_in[4];
    const float* b_hh0 = (const float*)d_in[5];
    const float* W_ih1 = (const float*)d_in[6];
    const float* W_hh1 = (const float*)d_in[7];
    const float* b_ih1 = (const float*)d_in[8];
    const float* b_hh1 = (const float*)d_in[9];
    const float* W_out = (const float*)d_in[10];
    const float* b_out = (const float*)d_in[11];

    dim3 grid(B_SZ / 16);   // 512 blocks x 8 waves = 4096 waves (4/SIMD)
    dim3 block(512);
    gru_xm<<<grid, block, 0, stream>>>(x, h_in, W_ih0, W_hh0, b_ih0, b_hh0,
                                       W_ih1, W_hh1, b_ih1, b_hh1,
                                       W_out, b_out, (float*)d_out);
}

// Round 4
// 230.314 us; speedup vs baseline: 1.1628x; 1.1628x over previous
//
#include <hip/hip_runtime.h>

// Fused 2-layer GRU, round 16: R13 structure + co-resident block de-phasing.
// S=256, B=8192, IN=1, H=32, L=2.
//
// 512 blocks x 256 thr (4 waves); block owns 16 batch elements.
// Waves 0,1: layer 0 (hidden half wl) -- true-dependency path, s_setprio(1).
// Waves 2,3: layer 1, lagged one step; ih-side MFMAs chained onto hh-side
//   accumulators; y-head MFMA alternates w2/w3 by timestep parity.
//
// NEW (R16): each CU hosts 2 phase-locked blocks; both bubble at the same
// barrier instant (measured ~34% idle). Half the blocks sleep ~768 cyc once
// before the hot loop so co-resident pairs interleave busy/bubble phases.
// Phase bit (blockIdx ^ blockIdx>>8)&1 differs for both (k,k+1) and
// (k,k+256) co-residency pairings. Cost if wrong: 0.3 us.
//
// Gate math (R13): merged-rcp combine, 5 trans/elem:
//   h' = [Nx*Nz - 2*Ez + (h-1)*Nx] * rcp(Nx*Nz)
// hm = h-1 maintained in registers.

#define S_LEN 256
#define B_SZ  8192
#define H_SZ  32
#define RS    40     // LDS row stride in shorts (80 B)

typedef __attribute__((ext_vector_type(8))) short short8;  // 8 bf16
typedef __attribute__((ext_vector_type(4))) float f32x4;   // MFMA C/D

#define MFMA(a, b, c) __builtin_amdgcn_mfma_f32_16x16x32_bf16(a, b, c, 0, 0, 0)

__device__ __forceinline__ unsigned short bf_rne1(float f) {
    union { float f; unsigned u; } x; x.f = f;
    unsigned u = x.u + 0x7fffu + ((x.u >> 16) & 1u);
    return (unsigned short)(u >> 16);
}

#if __has_builtin(__builtin_amdgcn_cvt_pk_bf16_f32)
typedef __bf16 bf16x2 __attribute__((ext_vector_type(2)));
__device__ __forceinline__ unsigned pk2(float a, float b) {
    union { bf16x2 v; unsigned u; } c;
    c.v = __builtin_amdgcn_cvt_pk_bf16_f32(a, b);
    return c.u;
}
#else
__device__ __forceinline__ unsigned pk2(float a, float b) {
    return (unsigned)bf_rne1(a) | ((unsigned)bf_rne1(b) << 16);
}
#endif

union Frag8 { short8 s8; unsigned u[4]; };

// Merged-rcp GRU combine: 3 exp2 + 2 rcp per element.
// Dr,Dz carry -log2e*(preact); Dn,Dxn carry 2log2e*(hh / ih parts of n).
// hm[r] = h-1 (updated in place). Returns packed bf16 pairs.
__device__ __forceinline__ uint2 gru_combine(const f32x4& Dr, const f32x4& Dz,
                                             const f32x4& Dn, const f32x4& Dxn,
                                             float* hm) {
    float v4[4];
#pragma unroll
    for (int r = 0; r < 4; ++r) {
        const float Er = __builtin_amdgcn_exp2f(Dr[r]);
        const float rg = __builtin_amdgcn_rcpf(1.0f + Er);           // r gate
        const float X  = __builtin_amdgcn_exp2f(fmaf(rg, Dn[r], Dxn[r]));
        const float Ez = __builtin_amdgcn_exp2f(Dz[r]);
        const float Nx = 1.0f + X;            // tanh denom
        const float Nz = 1.0f + Ez;           // z denom
        const float P  = Nx * Nz;
        float num = fmaf(-2.0f, Ez, P);       // Nx*Nz - 2*Ez
        num = fmaf(hm[r], Nx, num);           // + (h-1)*Nx
        const float v = num * __builtin_amdgcn_rcpf(P);
        hm[r] = v - 1.0f;
        v4[r] = v;
    }
    return make_uint2(pk2(v4[0], v4[1]), pk2(v4[2], v4[3]));
}

__global__ __launch_bounds__(256) void gru_xm(
    const float* __restrict__ x,      // (S,B,1)
    const float* __restrict__ h_in,   // (2,B,H)
    const float* __restrict__ W_ih0,  // (96,1)
    const float* __restrict__ W_hh0,  // (96,32)
    const float* __restrict__ b_ih0,  // (96)
    const float* __restrict__ b_hh0,  // (96)
    const float* __restrict__ W_ih1,  // (96,32)
    const float* __restrict__ W_hh1,  // (96,32)
    const float* __restrict__ b_ih1,  // (96)
    const float* __restrict__ b_hh1,  // (96)
    const float* __restrict__ W_out,  // (1,32)
    const float* __restrict__ b_out,  // (1)
    float* __restrict__ out)          // y (S*B) then h_state (2,B,H)
{
    __shared__ __align__(16) unsigned short sh0[2][16 * RS];  // h0 bf16
    __shared__ __align__(16) unsigned short sh1[2][16 * RS];  // h1 bf16
    __shared__ __align__(16) float sx[(S_LEN + 1) * 16];      // staged x (+pad)
    __shared__ __align__(16) float sy[S_LEN * 16];            // buffered y

    const int tid  = threadIdx.x;
    const int w    = tid >> 6;        // 0,1 -> layer 0; 2,3 -> layer 1
    const int lane = tid & 63;
    const int n    = lane & 15;       // batch col / A-row index
    const int q    = lane >> 4;       // quad
    const int base = blockIdx.x * 16;
    const int bn   = base + n;
    const int wl   = w & 1;           // hidden half within the layer
    const int phase = (blockIdx.x ^ (blockIdx.x >> 8)) & 1;

    // ---- stage x (coalesced float4, all waves) ----
    for (int s = tid; s < S_LEN * 4; s += 256) {
        const int t = s >> 2, c = s & 3;
        *(float4*)&sx[t * 16 + c * 4] = *(const float4*)&x[t * B_SZ + base + c * 4];
    }

    const float SRZ = -1.4426950408889634f;  // -log2(e)   (sigmoid gates)
    const float SN  =  2.8853900817779268f;  //  2*log2(e) (tanh gate)

    // ---- per-role persistent weights ----
    short8 A_h[3], A_i[3];                        // recurrent / (L1 ih | L0 x)
    f32x4  C_h[3], C_i3;
    short8 Awo = {0, 0, 0, 0, 0, 0, 0, 0};        // y head A-frag (w2,w3)
    short8 Bx  = {0, 0, 0, 0, 0, 0, 0, 0};        // x B-frag (w01), k=0 slot
    float  hm[4];                                  // own h half - 1, fp32

    if (w < 2) {
#pragma unroll
        for (int t = 0; t < 3; ++t) {
            const float sc = (t < 2) ? SRZ : SN;
            const int row = 32 * t + 16 * wl + n;
#pragma unroll
            for (int e = 0; e < 8; ++e)
                A_h[t][e] = (short)bf_rne1(W_hh0[row * H_SZ + q * 8 + e] * sc);
            // one-column x-weight fragment: k=0 only (q==0 && e==0)
#pragma unroll
            for (int e = 0; e < 8; ++e)
                A_i[t][e] = (q == 0 && e == 0)
                            ? (short)bf_rne1(W_ih0[row] * sc) : (short)0;
#pragma unroll
            for (int r = 0; r < 4; ++r) {
                const int g = 32 * t + 16 * wl + 4 * q + r;
                C_h[t][r] = (t < 2) ? SRZ * (b_ih0[g] + b_hh0[g])
                                    : SN * b_hh0[g];
                if (t == 2) C_i3[r] = SN * b_ih0[g];   // n-gate ih bias
            }
        }
#pragma unroll
        for (int r = 0; r < 4; ++r)
            hm[r] = h_in[bn * H_SZ + 16 * wl + 4 * q + r] - 1.0f;
    } else {
#pragma unroll
        for (int t = 0; t < 3; ++t) {
            const float sc = (t < 2) ? SRZ : SN;
            const int row = 32 * t + 16 * wl + n;
#pragma unroll
            for (int e = 0; e < 8; ++e) {
                A_h[t][e] = (short)bf_rne1(W_hh1[row * H_SZ + q * 8 + e] * sc);
                A_i[t][e] = (short)bf_rne1(W_ih1[row * H_SZ + q * 8 + e] * sc);
            }
#pragma unroll
            for (int r = 0; r < 4; ++r) {
                const int g = 32 * t + 16 * wl + 4 * q + r;
                C_h[t][r] = (t < 2) ? SRZ * (b_ih1[g] + b_hh1[g])
                                    : SN * b_hh1[g];
                if (t == 2) C_i3[r] = SN * b_ih1[g];
            }
        }
#pragma unroll
        for (int r = 0; r < 4; ++r)
            hm[r] = h_in[B_SZ * H_SZ + bn * H_SZ + 16 * wl + 4 * q + r] - 1.0f;
        if (w == 2 || w == 3) {
#pragma unroll
            for (int e = 0; e < 8; ++e)
                Awo[e] = (n == 0) ? (short)bf_rne1(W_out[q * 8 + e]) : (short)0;
        }
    }
    const f32x4 Z4 = {0.f, 0.f, 0.f, 0.f};
    const float bout = b_out[0];

    // ---- initial B fragments (bf16 from h_in) ----
    short8 B0, B1;   // w01: B0 = h0(i-1). w23: B0 = h0(i-1), B1 = h1(i-2).
    {
        const float* hsrc = h_in + (size_t)(w >= 2) * B_SZ * H_SZ + bn * H_SZ + q * 8;
        Frag8 f;
        const float4 a = *(const float4*)&hsrc[0];
        const float4 b = *(const float4*)&hsrc[4];
        f.u[0] = pk2(a.x, a.y); f.u[1] = pk2(a.z, a.w);
        f.u[2] = pk2(b.x, b.y); f.u[3] = pk2(b.z, b.w);
        if (w < 2) B0 = f.s8; else B1 = f.s8;
    }

    const int wroff = n * RS + 16 * wl + 4 * q;   // b64 write (shorts)
    const int rdoff = n * RS + 8 * q;             // b128 read (shorts)

    __syncthreads();   // x staged

    // De-phase co-resident blocks: half-period offset (~768 cyc) for one
    // of each pair so A's compute fills B's barrier/ds_read bubble.
    if (phase) __builtin_amdgcn_s_sleep(12);

    float xcur = sx[n];
    if (w < 2) __builtin_amdgcn_s_setprio(1);   // true-dep path issues first

    // ================= iter 0 (peeled): w01 compute h0(0) =================
    if (w < 2) {
        Frag8 bxu; bxu.s8 = Bx; bxu.u[0] = pk2(xcur, xcur); Bx = bxu.s8;
        f32x4 Dr = MFMA(A_h[0], B0, C_h[0]);  Dr = MFMA(A_i[0], Bx, Dr);
        f32x4 Dz = MFMA(A_h[1], B0, C_h[1]);  Dz = MFMA(A_i[1], Bx, Dz);
        f32x4 Dn = MFMA(A_h[2], B0, C_h[2]);
        f32x4 Dxn = MFMA(A_i[2], Bx, C_i3);
        *(uint2*)&sh0[0][wroff] = gru_combine(Dr, Dz, Dn, Dxn, hm);
        xcur = sx[16 + n];   // x(1)
    }
    __syncthreads();
    B0 = *(const short8*)&sh0[0][rdoff];   // h0(0) for all waves

    // ================= hot loop i = 1 .. S-1 (no predication) ==============
#pragma unroll 2
    for (int i = 1; i < S_LEN; ++i) {
        const int buf = i & 1;
        if (w < 2) {
            // h0(i) from B0 = h0(i-1): the true-dependency path.
            Frag8 bxu; bxu.s8 = Bx; bxu.u[0] = pk2(xcur, xcur); Bx = bxu.s8;
            f32x4 Dr = MFMA(A_h[0], B0, C_h[0]);  Dr = MFMA(A_i[0], Bx, Dr);
            f32x4 Dz = MFMA(A_h[1], B0, C_h[1]);  Dz = MFMA(A_i[1], Bx, Dz);
            f32x4 Dn = MFMA(A_h[2], B0, C_h[2]);
            f32x4 Dxn = MFMA(A_i[2], Bx, C_i3);
            *(uint2*)&sh0[buf][wroff] = gru_combine(Dr, Dz, Dn, Dxn, hm);
            xcur = sx[(i + 1) * 16 + n];   // read-only prefetch, pre-barrier
        } else {
            // h1(i-1) from B1 = h1(i-2), B0 = h0(i-1): prefetched last iter.
            // ih-side chained onto hh-side accumulators (no combine-adds).
            f32x4 Gr = MFMA(A_h[0], B1, C_h[0]);  Gr = MFMA(A_i[0], B0, Gr);
            f32x4 Gz = MFMA(A_h[1], B1, C_h[1]);  Gz = MFMA(A_i[1], B0, Gz);
            f32x4 Un = MFMA(A_h[2], B1, C_h[2]);
            f32x4 Vn = MFMA(A_i[2], B0, C_i3);
            *(uint2*)&sh1[buf][wroff] = gru_combine(Gr, Gz, Un, Vn, hm);
        }

        __syncthreads();   // lgkm-only drain

        if (w < 2) {
            B0 = *(const short8*)&sh0[buf][rdoff];          // h0(i)
        } else {
            B0 = *(const short8*)&sh0[buf][rdoff];          // h0(i)
            B1 = *(const short8*)&sh1[buf][rdoff];          // h1(i-1)
            if (w == 2 + ((i - 1) & 1)) {
                // y(i-1) = W_out . h1(i-1): one MFMA, row 0 = result.
                // Alternates w2/w3 so neither wave straggles every iter.
                const f32x4 yD = MFMA(Awo, B1, Z4);
                if (lane < 16) sy[(i - 1) * 16 + n] = yD[0];
            }
        }
    }

    // ================= iter S (peeled): w23 compute h1(S-1) ================
    if (w >= 2) {
        f32x4 Gr = MFMA(A_h[0], B1, C_h[0]);  Gr = MFMA(A_i[0], B0, Gr);
        f32x4 Gz = MFMA(A_h[1], B1, C_h[1]);  Gz = MFMA(A_i[1], B0, Gz);
        f32x4 Un = MFMA(A_h[2], B1, C_h[2]);
        f32x4 Vn = MFMA(A_i[2], B0, C_i3);
        *(uint2*)&sh1[0][wroff] = gru_combine(Gr, Gz, Un, Vn, hm);
    }
    __syncthreads();
    if (w == 2 + ((S_LEN - 1) & 1)) {
        B1 = *(const short8*)&sh1[0][rdoff];               // h1(S-1)
        const f32x4 yD = MFMA(Awo, B1, Z4);
        if (lane < 16) sy[(S_LEN - 1) * 16 + n] = yD[0];
    }
    __syncthreads();   // sy complete

    // ---- flush y (coalesced float4 + bias) ----
    for (int s = tid; s < S_LEN * 4; s += 256) {
        const int t = s >> 2, c = s & 3;
        const float4 a = *(const float4*)&sy[t * 16 + c * 4];
        *(float4*)&out[t * B_SZ + base + c * 4] =
            make_float4(a.x + bout, a.y + bout, a.z + bout, a.w + bout);
    }

    // ---- final h_state: out = y (S*B) ++ h0 (B*H) ++ h1 (B*H) ----
    const size_t hoff = (size_t)S_LEN * B_SZ + (size_t)(w >= 2) * B_SZ * H_SZ;
    *(float4*)&out[hoff + bn * H_SZ + 16 * wl + 4 * q] =
        make_float4(hm[0] + 1.0f, hm[1] + 1.0f, hm[2] + 1.0f, hm[3] + 1.0f);
}

extern "C" void kernel_launch(void* const* d_in, const int* in_sizes, int n_in,
                              void* d_out, int out_size, void* d_ws, size_t ws_size,
                              hipStream_t stream) {
    (void)in_sizes; (void)n_in; (void)out_size; (void)d_ws; (void)ws_size;
    const float* x     = (const float*)d_in[0];
    const float* h_in  = (const float*)d_in[1];
    const float* W_ih0 = (const float*)d_in[2];
    const float* W_hh0 = (const float*)d_in[3];
    const float* b_ih0 = (const float*)d_in[4];
    const float* b_hh0 = (const float*)d_in[5];
    const float* W_ih1 = (const float*)d_in[6];
    const float* W_hh1 = (const float*)d_in[7];
    const float* b_ih1 = (const float*)d_in[8];
    const float* b_hh1 = (const float*)d_in[9];
    const float* W_out = (const float*)d_in[10];
    const float* b_out = (const float*)d_in[11];

    dim3 grid(B_SZ / 16);   // 512 blocks x 4 waves = 2048 waves (2/SIMD)
    dim3 block(256);
    gru_xm<<<grid, block, 0, stream>>>(x, h_in, W_ih0, W_hh0, b_ih0, b_hh0,
                                       W_ih1, W_hh1, b_ih1, b_hh1,
                                       W_out, b_out, (float*)d_out);
}